// Round 5
// baseline (300.759 us; speedup 1.0000x reference)
//
#include <hip/hip_runtime.h>
#include <stdint.h>

// DetectPeaksTM: per row of nt=8192 fp32, x=|xcorr|, sliding max window K=301
// (pad 150), scores = x where x==windowmax else 0, top-2 (score, idx).
// Outputs concatenated: [nrows*2] f32 scores, then [nrows*2] indices written
// as float values (harness reads whole d_out as float32; idx<8192 exact).
//
// R5: split into two kernels so the 201 MB stream runs pure.
//  Pass A (seg_pass): NO LDS, NO barriers. Per 32-elem segment produce
//    {segmax, 32-bit tie mask of positions == segmax} via 6 shfl_xor per
//    float4-group, packed float2 -> ws (nrows*256*8 B = 12.6 MB).
//    Every true peak satisfies x[t]==segmax(t's seg) (own seg is inside the
//    +-150 window), and the mask enumerates ALL tied positions -> exact.
//  Pass B (peaks_pass): 1 block/row, 1 thread/segment. Stage segmaxes into
//    padded LDS; tier1 = 9 consecutive value-masked LDS reads (interior segs,
//    includes own seg -> rejects ~8/9 of ~256 cands/row); tier2 = exact edge
//    check via <=16 element-masked float4 re-reads of x (L3-warm, ~28
//    survivors/row); top-2 via monotone key (bits(v)<<32)|(8191-t)
//    (value desc, idx asc on ties == jax.lax.top_k order).

#define NT 8192
#define RADIUS 150
#define NSEG 256          // 32-elem segments per row

// ---------------- Pass A: pure streaming summarizer ----------------
__global__ __launch_bounds__(256, 8) void seg_pass(
    const float* __restrict__ x, float2* __restrict__ ws)
{
    const int row = blockIdx.x;
    const int tid = threadIdx.x;
    const float4* g4 = (const float4*)(x + (size_t)row * NT);
    float2* wrow = ws + (size_t)row * NSEG;

    float4 vv[8];
#pragma unroll
    for (int it = 0; it < 8; ++it) vv[it] = g4[it * 256 + tid];

    const int sh = (tid & 7) * 4;     // this lane's 4 elems' bit positions
#pragma unroll
    for (int it = 0; it < 8; ++it) {
        const float4 v = vv[it];
        const float ax = fabsf(v.x), ay = fabsf(v.y);
        const float az = fabsf(v.z), aw = fabsf(v.w);
        const float cm4 = fmaxf(fmaxf(ax, ay), fmaxf(az, aw));
        // lanes 8k..8k+7 (same (it*256+tid)>>3) hold one 32-seg
        float cm = fmaxf(cm4, __shfl_xor(cm4, 1));
        cm = fmaxf(cm, __shfl_xor(cm, 2));
        cm = fmaxf(cm, __shfl_xor(cm, 4));
        unsigned msk = ((ax == cm ? 1u : 0u) |
                        (ay == cm ? 2u : 0u) |
                        (az == cm ? 4u : 0u) |
                        (aw == cm ? 8u : 0u)) << sh;
        msk |= __shfl_xor((int)msk, 1);
        msk |= __shfl_xor((int)msk, 2);
        msk |= __shfl_xor((int)msk, 4);
        if ((tid & 7) == 0) {
            const int seg = (it * 256 + tid) >> 3;
            wrow[seg] = make_float2(cm, __uint_as_float(msk));
        }
    }
}

// ---------------- Pass B: per-row verify + top-2 ----------------
__global__ __launch_bounds__(256) void peaks_pass(
    const float* __restrict__ x, const float2* __restrict__ ws,
    float* __restrict__ out, int nrows)
{
    const int row = blockIdx.x;
    const int s = threadIdx.x;                 // this thread's segment

    __shared__ float mm[8 + NSEG + 16];        // zero-padded seg maxes
    __shared__ unsigned long long wred[8];
    float* const mmp = mm + 8;

    const float2 w = ws[(size_t)row * NSEG + s];
    const float sval = w.x;
    unsigned msk = __float_as_uint(w.y);

    if (s < 8) mm[s] = 0.0f;
    if (s < 16) mm[8 + NSEG + s] = 0.0f;
    mmp[s] = sval;
    __syncthreads();

    const float4* g4 = (const float4*)(x + (size_t)row * NT);
    unsigned long long k1 = 0ull, k2 = 0ull;

    while (msk) {
        const int b = __builtin_ctz(msk); msk &= (msk - 1u);
        const int t = (s << 5) + b;
        const float val = sval;                // == x[t]
        const int l = max(t - RADIUS, 0);
        const int r = min(t + RADIUS, NT - 1);
        const int il = l >> 5, ir = r >> 5;    // il < ir always
        // tier1: interior full segs [il+1, ir-1], len in [3,9]
        const int len = ir - il - 1;
        const float* mp = &mmp[il + 1];
        float iv[9];
#pragma unroll
        for (int j = 0; j < 9; ++j) iv[j] = mp[j];
        float im = 0.0f;
#pragma unroll
        for (int j = 0; j < 9; ++j) im = fmaxf(im, (j < len) ? iv[j] : 0.0f);
        if (im > val) continue;                // beaten inside window
        // tier2: exact edge check via global re-reads (L3-warm)
        float em = 0.0f;
        {   // head [l, (il+1)*32): blocks l>>2 .. il*8+7, <=8, j==0 partial
            const int hb0 = l >> 2;
            const int hbN = il * 8 + 8;
#pragma unroll
            for (int j = 0; j < 8; ++j) {
                const int bb = hb0 + j;
                const float4 q = g4[bb];
                float bm;
                if (j == 0) {
                    bm = (4 * bb + 0 >= l) ? fabsf(q.x) : 0.0f;
                    bm = fmaxf(bm, (4 * bb + 1 >= l) ? fabsf(q.y) : 0.0f);
                    bm = fmaxf(bm, (4 * bb + 2 >= l) ? fabsf(q.z) : 0.0f);
                    bm = fmaxf(bm, fabsf(q.w));        // 4bb+3 >= l always
                } else {
                    bm = fmaxf(fmaxf(fabsf(q.x), fabsf(q.y)),
                               fmaxf(fabsf(q.z), fabsf(q.w)));
                }
                em = fmaxf(em, (bb < hbN) ? bm : 0.0f);
            }
        }
        {   // tail [ir*32, r]: blocks ir*8 .. r>>2, elem-masked by <= r
            const int tb0 = ir * 8;
#pragma unroll
            for (int j = 0; j < 8; ++j) {
                const int bb = tb0 + j;
                const float4 q = g4[bb];
                float bm;
                bm = (4 * bb + 0 <= r) ? fabsf(q.x) : 0.0f;
                bm = fmaxf(bm, (4 * bb + 1 <= r) ? fabsf(q.y) : 0.0f);
                bm = fmaxf(bm, (4 * bb + 2 <= r) ? fabsf(q.z) : 0.0f);
                bm = fmaxf(bm, (4 * bb + 3 <= r) ? fabsf(q.w) : 0.0f);
                em = fmaxf(em, bm);
            }
        }
        if (em > val) continue;
        const unsigned long long key =
            ((unsigned long long)__float_as_uint(val) << 32) |
            (unsigned)(NT - 1 - t);
        if (key > k1) { k2 = k1; k1 = key; }
        else if (key > k2) { k2 = key; }
    }

    // top-2 reduction: wave shuffle, then 4 waves via LDS
#pragma unroll
    for (int off = 32; off >= 1; off >>= 1) {
        unsigned long long o1 = __shfl_down(k1, off);
        unsigned long long o2 = __shfl_down(k2, off);
        unsigned long long hi = (k1 > o1) ? k1 : o1;
        unsigned long long lo = (k1 > o1) ? o1 : k1;
        unsigned long long s2 = (k2 > o2) ? k2 : o2;
        k1 = hi;
        k2 = (lo > s2) ? lo : s2;
    }
    const int wave = s >> 6;
    if ((s & 63) == 0) { wred[wave * 2] = k1; wred[wave * 2 + 1] = k2; }
    __syncthreads();

    if (s == 0) {
        unsigned long long a1 = wred[0], a2 = wred[1];
        for (int wv = 1; wv < 4; ++wv) {
            unsigned long long o1 = wred[wv * 2], o2 = wred[wv * 2 + 1];
            unsigned long long hi = (a1 > o1) ? a1 : o1;
            unsigned long long lo = (a1 > o1) ? o1 : a1;
            unsigned long long s2 = (a2 > o2) ? a2 : o2;
            a1 = hi;
            a2 = (lo > s2) ? lo : s2;
        }
        float s1v, s2v; int i1, i2;
        if (a1 == 0ull) { s1v = 0.0f; i1 = 0; }
        else {
            s1v = __uint_as_float((unsigned)(a1 >> 32));
            i1 = (NT - 1) - (int)(a1 & 0xffffffffull);
        }
        if (a2 == 0ull) {   // <2 peaks: second entry is first zero-score slot
            s2v = 0.0f;
            i2 = (i1 == 0) ? 1 : 0;
        } else {
            s2v = __uint_as_float((unsigned)(a2 >> 32));
            i2 = (NT - 1) - (int)(a2 & 0xffffffffull);
        }
        out[row * 2 + 0] = s1v;
        out[row * 2 + 1] = s2v;
        float* oi = out + (size_t)nrows * 2;
        oi[row * 2 + 0] = (float)i1;
        oi[row * 2 + 1] = (float)i2;
    }
}

extern "C" void kernel_launch(void* const* d_in, const int* in_sizes, int n_in,
                              void* d_out, int out_size, void* d_ws, size_t ws_size,
                              hipStream_t stream) {
    const float* x = (const float*)d_in[0];
    // d_in[1] = nlag (unused by the reference)
    float* out = (float*)d_out;
    const int nrows = in_sizes[0] / NT;      // 32*3*64 = 6144
    float2* ws = (float2*)d_ws;              // nrows*256*8 B = 12.6 MB
    seg_pass<<<nrows, 256, 0, stream>>>(x, ws);
    peaks_pass<<<nrows, 256, 0, stream>>>(x, ws, out, nrows);
}

// Round 6
// 273.764 us; speedup vs baseline: 1.0986x; 1.0986x over previous
//
#include <hip/hip_runtime.h>
#include <stdint.h>

// DetectPeaksTM: per row of nt=8192 fp32, x=|xcorr|, sliding max window K=301
// (pad 150), scores = x where x==windowmax else 0, top-2 (score, idx).
// Outputs concatenated: [nrows*2] f32 scores, then [nrows*2] indices written
// as float values (harness reads whole d_out as float32; idx<8192 exact).
//
// R6: segment-per-thread. Thread s owns the 32 consecutive elems of segment
// s (8 strided float4 loads; every 64-B granule fetched exactly once).
//  P1: segmax fully in-register (NO shuffles), one ds_write of m[s].
//  P2a: 9 consecutive neighbor segmaxes m[s-4..s+4] (~3 DS reads). Since
//       segs s-3..s+3 are inside EVERY +-150 window of seg s, the necessary
//       condition sval >= max(m[s-3..s+3]) rejects ~6/7 segments.
//  P2b: survivors only (one divergent pass, ties enumerated from registers):
//       tier1 interior-seg max from the 9 cached regs (masked by [il+1,ir-1]),
//       tier2 exact edge check via 16 element-masked L1-warm float4 loads.
//  P3: top-2 via monotone key (bits(v)<<32)|(8191-t) (value desc, idx asc on
//      ties == jax.lax.top_k order), wave shuffle + tiny LDS reduce.

#define NT 8192
#define RADIUS 150
#define NSEG 256

__global__ __launch_bounds__(256) void detect_peaks_kernel(
    const float* __restrict__ x, float* __restrict__ out, int nrows)
{
    const int row = blockIdx.x;
    const int s = threadIdx.x;                 // this thread's segment

    __shared__ float mm[8 + NSEG + 16];        // zero-padded seg maxes
    __shared__ unsigned long long wred[8];
    float* const mmp = mm + 8;

    const float4* g4 = (const float4*)(x + (size_t)row * NT);

    if (s < 8) mm[s] = 0.0f;
    if (s < 16) mm[8 + NSEG + s] = 0.0f;

    // ---- P1: load own segment, abs, in-register segmax ----
    float4 vv[8];
#pragma unroll
    for (int j = 0; j < 8; ++j) vv[j] = g4[s * 8 + j];

    float sval = 0.0f;
#pragma unroll
    for (int j = 0; j < 8; ++j) {
        float4 v = vv[j];
        v.x = fabsf(v.x); v.y = fabsf(v.y);
        v.z = fabsf(v.z); v.w = fabsf(v.w);
        vv[j] = v;
        sval = fmaxf(sval, fmaxf(fmaxf(v.x, v.y), fmaxf(v.z, v.w)));
    }
    mmp[s] = sval;
    __syncthreads();

    // ---- P2a: neighbor prefilter ----
    float nbr[9];                              // m[s-4 .. s+4]
#pragma unroll
    for (int j = 0; j < 9; ++j) nbr[j] = mmp[s - 4 + j];
    float nb7 = 0.0f;
#pragma unroll
    for (int j = 1; j <= 7; ++j) nb7 = fmaxf(nb7, nbr[j]);   // s-3..s+3

    unsigned long long k1 = 0ull, k2 = 0ull;

    if (!(nb7 > sval)) {
        // ---- P2b: survivor -- enumerate ties, exact verification ----
        unsigned eqm = 0u;
#pragma unroll
        for (int j = 0; j < 8; ++j) {
            eqm |= (vv[j].x == sval ? 1u : 0u) << (4 * j + 0);
            eqm |= (vv[j].y == sval ? 1u : 0u) << (4 * j + 1);
            eqm |= (vv[j].z == sval ? 1u : 0u) << (4 * j + 2);
            eqm |= (vv[j].w == sval ? 1u : 0u) << (4 * j + 3);
        }
        while (eqm) {
            const int b = __builtin_ctz(eqm); eqm &= (eqm - 1u);
            const int t = (s << 5) + b;
            const int l = max(t - RADIUS, 0);
            const int r = min(t + RADIUS, NT - 1);
            const int il = l >> 5, ir = r >> 5;   // il in {s-5,s-4}, ir in {s+4,s+5}
            // tier1: interior segs [il+1, ir-1] subset of [s-4, s+4] -> regs
            float im = 0.0f;
#pragma unroll
            for (int j = 0; j < 9; ++j) {
                const int seg = s - 4 + j;
                im = fmaxf(im, (seg >= il + 1 && seg <= ir - 1) ? nbr[j] : 0.0f);
            }
            if (im > sval) continue;              // beaten inside window
            // tier2: exact edge check (L1-warm float4 re-reads)
            float em = 0.0f;
            {   // head [l, (il+1)*32): blocks l>>2 .. il*8+7, j==0 partial
                const int hb0 = l >> 2;
                const int hbN = il * 8 + 8;
#pragma unroll
                for (int j = 0; j < 8; ++j) {
                    const int bb = hb0 + j;
                    const float4 q = g4[bb];
                    float bm;
                    if (j == 0) {
                        bm = (4 * bb + 0 >= l) ? fabsf(q.x) : 0.0f;
                        bm = fmaxf(bm, (4 * bb + 1 >= l) ? fabsf(q.y) : 0.0f);
                        bm = fmaxf(bm, (4 * bb + 2 >= l) ? fabsf(q.z) : 0.0f);
                        bm = fmaxf(bm, fabsf(q.w));      // 4bb+3 >= l always
                    } else {
                        bm = fmaxf(fmaxf(fabsf(q.x), fabsf(q.y)),
                                   fmaxf(fabsf(q.z), fabsf(q.w)));
                    }
                    em = fmaxf(em, (bb < hbN) ? bm : 0.0f);
                }
            }
            {   // tail [ir*32, r]: blocks ir*8 .. ir*8+7, elem-masked by <= r
                const int tb0 = ir * 8;
#pragma unroll
                for (int j = 0; j < 8; ++j) {
                    const int bb = tb0 + j;
                    const float4 q = g4[bb];
                    float bm;
                    bm = (4 * bb + 0 <= r) ? fabsf(q.x) : 0.0f;
                    bm = fmaxf(bm, (4 * bb + 1 <= r) ? fabsf(q.y) : 0.0f);
                    bm = fmaxf(bm, (4 * bb + 2 <= r) ? fabsf(q.z) : 0.0f);
                    bm = fmaxf(bm, (4 * bb + 3 <= r) ? fabsf(q.w) : 0.0f);
                    em = fmaxf(em, bm);
                }
            }
            if (em > sval) continue;
            const unsigned long long key =
                ((unsigned long long)__float_as_uint(sval) << 32) |
                (unsigned)(NT - 1 - t);
            if (key > k1) { k2 = k1; k1 = key; }
            else if (key > k2) { k2 = key; }
        }
    }

    // ---- P3: top-2 reduction (wave shuffle, then 4 waves via LDS) ----
#pragma unroll
    for (int off = 32; off >= 1; off >>= 1) {
        unsigned long long o1 = __shfl_down(k1, off);
        unsigned long long o2 = __shfl_down(k2, off);
        unsigned long long hi = (k1 > o1) ? k1 : o1;
        unsigned long long lo = (k1 > o1) ? o1 : k1;
        unsigned long long s2 = (k2 > o2) ? k2 : o2;
        k1 = hi;
        k2 = (lo > s2) ? lo : s2;
    }
    const int wave = s >> 6;
    if ((s & 63) == 0) { wred[wave * 2] = k1; wred[wave * 2 + 1] = k2; }
    __syncthreads();

    if (s == 0) {
        unsigned long long a1 = wred[0], a2 = wred[1];
        for (int wv = 1; wv < 4; ++wv) {
            unsigned long long o1 = wred[wv * 2], o2 = wred[wv * 2 + 1];
            unsigned long long hi = (a1 > o1) ? a1 : o1;
            unsigned long long lo = (a1 > o1) ? o1 : a1;
            unsigned long long s2 = (a2 > o2) ? a2 : o2;
            a1 = hi;
            a2 = (lo > s2) ? lo : s2;
        }
        float s1v, s2v; int i1, i2;
        if (a1 == 0ull) { s1v = 0.0f; i1 = 0; }
        else {
            s1v = __uint_as_float((unsigned)(a1 >> 32));
            i1 = (NT - 1) - (int)(a1 & 0xffffffffull);
        }
        if (a2 == 0ull) {   // <2 peaks: second entry is first zero-score slot
            s2v = 0.0f;
            i2 = (i1 == 0) ? 1 : 0;
        } else {
            s2v = __uint_as_float((unsigned)(a2 >> 32));
            i2 = (NT - 1) - (int)(a2 & 0xffffffffull);
        }
        out[row * 2 + 0] = s1v;
        out[row * 2 + 1] = s2v;
        float* oi = out + (size_t)nrows * 2;
        oi[row * 2 + 0] = (float)i1;
        oi[row * 2 + 1] = (float)i2;
    }
}

extern "C" void kernel_launch(void* const* d_in, const int* in_sizes, int n_in,
                              void* d_out, int out_size, void* d_ws, size_t ws_size,
                              hipStream_t stream) {
    const float* x = (const float*)d_in[0];
    // d_in[1] = nlag (unused by the reference)
    float* out = (float*)d_out;
    const int nrows = in_sizes[0] / NT;      // 32*3*64 = 6144
    detect_peaks_kernel<<<nrows, 256, 0, stream>>>(x, out, nrows);
}